// Round 1
// baseline (120.176 us; speedup 1.0000x reference)
//
#include <hip/hip_runtime.h>

#define BATCH   256
#define FG_CAP  64
#define BG_CAP  192
#define NB_CAP  256

// ---------------------------------------------------------------------------
// Kernel 1: per-ROI IoU argmax/max vs all GT boxes  +  gt one-hot argmax.
// packed[i] = best_gt_index | (cls << 16), cls: 0=neither, 1=fg, 2=bg
// IoU arithmetic uses explicit round-to-nearest intrinsics in the reference's
// exact op order so threshold comparisons match numpy bit-for-bit (no FMA
// contraction allowed to shift values at the 0.5 / 0.1 boundaries).
// ---------------------------------------------------------------------------
__global__ __launch_bounds__(256) void pt_classify(
    const float* __restrict__ props, const float* __restrict__ gtb,
    const float* __restrict__ gtl,
    int* __restrict__ packed, int* __restrict__ gtcls,
    int n_prop, int K, int C, int n_total, int roi_blocks)
{
    if ((int)blockIdx.x >= roi_blocks) {
        // gt-class blocks: argmax of one-hot label rows (first-max)
        int t = ((int)blockIdx.x - roi_blocks) * 256 + (int)threadIdx.x;
        if (t < K) {
            const float* row = gtl + (size_t)t * C;
            float best = row[0]; int bc = 0;
            for (int c = 1; c < C; ++c) {
                float v = row[c];
                if (v > best) { best = v; bc = c; }
            }
            gtcls[t] = bc;
        }
        return;
    }

    __shared__ float4 s_gt[512];
    __shared__ float  s_area[512];
    for (int k = threadIdx.x; k < K; k += 256) {
        float x1 = gtb[4*k+0], y1 = gtb[4*k+1], x2 = gtb[4*k+2], y2 = gtb[4*k+3];
        s_gt[k] = make_float4(x1, y1, x2, y2);
        s_area[k] = __fmul_rn(__fadd_rn(__fsub_rn(x2, x1), 1.0f),
                              __fadd_rn(__fsub_rn(y2, y1), 1.0f));
    }
    __syncthreads();

    int i = (int)blockIdx.x * 256 + (int)threadIdx.x;
    if (i >= n_total) return;

    float4 a;
    if (i < n_prop) a = ((const float4*)props)[i];
    else            a = ((const float4*)gtb)[i - n_prop];

    float area_a = __fmul_rn(__fadd_rn(__fsub_rn(a.z, a.x), 1.0f),
                             __fadd_rn(__fsub_rn(a.w, a.y), 1.0f));

    float best = -1.0f; int bestk = 0;
    for (int k = 0; k < K; ++k) {
        float4 g = s_gt[k];
        float iw = fmaxf(__fadd_rn(__fsub_rn(fminf(a.z, g.z), fmaxf(a.x, g.x)), 1.0f), 0.0f);
        float ih = fmaxf(__fadd_rn(__fsub_rn(fminf(a.w, g.w), fmaxf(a.y, g.y)), 1.0f), 0.0f);
        float inter = __fmul_rn(iw, ih);
        float denom = __fsub_rn(__fadd_rn(area_a, s_area[k]), inter);
        float iou   = __fdiv_rn(inter, denom);
        if (iou > best) { best = iou; bestk = k; }   // strict >  == first-max (jnp.argmax)
    }

    int cls = 0;
    if (best >= 0.5f)      cls = 1;   // fg
    else if (best >= 0.1f) cls = 2;   // bg
    packed[i] = bestk | (cls << 16);
}

// ---------------------------------------------------------------------------
// Kernel 2: stable (index-ordered) compaction of fg / bg / non-bg lists.
// Single 1024-thread block, ballot + cross-wave scan, early exit once
// 64 fg and 192 bg have been found. non-bg list is the fallback for the
// degenerate case n_bg < 192 (matches bg_sorted semantics past n_bg).
// ---------------------------------------------------------------------------
__global__ __launch_bounds__(1024) void pt_compact(
    const int* __restrict__ packed,
    int* __restrict__ fg_list, int* __restrict__ bg_list,
    int* __restrict__ nb_list, int* __restrict__ counts, int n_total)
{
    __shared__ int w_fg[16], w_bg[16], w_nb[16];
    __shared__ int run[3];
    __shared__ int done;
    int tid = threadIdx.x;
    if (tid == 0) { run[0] = 0; run[1] = 0; run[2] = 0; done = 0; }
    __syncthreads();

    int lane = tid & 63, wave = tid >> 6;
    unsigned long long ltmask = (1ull << lane) - 1ull;

    for (int base = 0; base < n_total; base += 1024) {
        int idx = base + tid;
        int cls = -1;
        if (idx < n_total) cls = packed[idx] >> 16;
        bool pfg = (cls == 1);
        bool pbg = (cls == 2);
        bool pnb = (cls == 0) || (cls == 1);   // in-range and not bg

        unsigned long long bfg = __ballot(pfg);
        unsigned long long bbg = __ballot(pbg);
        unsigned long long bnb = __ballot(pnb);
        if (lane == 0) {
            w_fg[wave] = __popcll(bfg);
            w_bg[wave] = __popcll(bbg);
            w_nb[wave] = __popcll(bnb);
        }
        int r0 = run[0], r1 = run[1], r2 = run[2];
        __syncthreads();

        int pf = 0, pb = 0, pn = 0;
        for (int w = 0; w < wave; ++w) { pf += w_fg[w]; pb += w_bg[w]; pn += w_nb[w]; }
        int rfg = r0 + pf + (int)__popcll(bfg & ltmask);
        int rbg = r1 + pb + (int)__popcll(bbg & ltmask);
        int rnb = r2 + pn + (int)__popcll(bnb & ltmask);
        if (pfg && rfg < FG_CAP) fg_list[rfg] = idx;
        if (pbg && rbg < BG_CAP) bg_list[rbg] = idx;
        if (pnb && rnb < NB_CAP) nb_list[rnb] = idx;
        __syncthreads();

        if (tid == 0) {
            int sf = 0, sb = 0, sn = 0;
            for (int w = 0; w < 16; ++w) { sf += w_fg[w]; sb += w_bg[w]; sn += w_nb[w]; }
            run[0] += sf; run[1] += sb; run[2] += sn;
            if (run[0] >= FG_CAP && run[1] >= BG_CAP) done = 1;
        }
        __syncthreads();
        if (done) break;
    }
    if (tid == 0) { counts[0] = run[0]; counts[1] = run[1]; counts[2] = run[2]; }
}

// ---------------------------------------------------------------------------
// Kernel 3: one block per output slot. Fills rois (4), labels one-hot (C),
// bbox_targets (4C) — every element written (d_out is poisoned).
// ---------------------------------------------------------------------------
__global__ __launch_bounds__(128) void pt_output(
    const float* __restrict__ props, const float* __restrict__ gtb,
    const int* __restrict__ packed, const int* __restrict__ gtcls,
    const int* __restrict__ fg_list, const int* __restrict__ bg_list,
    const int* __restrict__ nb_list, const int* __restrict__ counts,
    float* __restrict__ out, int n_prop, int K, int C)
{
    __shared__ float sh[8];     // roi x1 y1 x2 y2, tx ty tw th
    __shared__ int   sh_label;
    int s = blockIdx.x;

    if (threadIdx.x == 0) {
        int fg_total = counts[0], bg_total = counts[1];
        int fg_count = min(FG_CAP, fg_total);
        bool is_fg = (s < fg_count);
        int keep;
        if (is_fg) {
            keep = fg_list[s];
        } else {
            int j = s - fg_count;
            keep = (j < bg_total) ? bg_list[j] : nb_list[j - bg_total];
        }
        int pk = packed[keep];
        int assign = pk & 0xFFFF;
        int label = is_fg ? gtcls[assign] : 0;   // labels_kept (0 for bg/invalid slots)

        float4 roi;
        if (keep < n_prop) roi = ((const float4*)props)[keep];
        else               roi = ((const float4*)gtb)[keep - n_prop];
        float4 g = ((const float4*)gtb)[assign];

        // bbox_transform (continuous math — precision non-critical)
        float ew  = roi.z - roi.x + 1.0f;
        float eh  = roi.w - roi.y + 1.0f;
        float ecx = roi.x + 0.5f * ew;
        float ecy = roi.y + 0.5f * eh;
        float gw  = g.z - g.x + 1.0f;
        float gh  = g.w - g.y + 1.0f;
        float gcx = g.x + 0.5f * gw;
        float gcy = g.y + 0.5f * gh;
        sh[0] = roi.x; sh[1] = roi.y; sh[2] = roi.z; sh[3] = roi.w;
        sh[4] = (gcx - ecx) / ew;
        sh[5] = (gcy - ecy) / eh;
        sh[6] = logf(gw / ew);
        sh[7] = logf(gh / eh);
        sh_label = label;
    }
    __syncthreads();

    int label = sh_label;

    // output 0: rois (BATCH x 4)
    if (threadIdx.x < 4) out[s * 4 + threadIdx.x] = sh[threadIdx.x];

    // output 1: labels one-hot (BATCH x C)
    float* outl = out + 4 * BATCH;
    for (int c = threadIdx.x; c < C; c += 128)
        outl[s * C + c] = (c == label) ? 1.0f : 0.0f;

    // output 2: bbox_targets (BATCH x 4C)
    float* outb = out + 4 * BATCH + BATCH * C;
    int bw = 4 * C;
    for (int c = threadIdx.x; c < bw; c += 128) {
        float v = 0.0f;
        if (label > 0 && (c >> 2) == label) v = sh[4 + (c & 3)];
        outb[s * bw + c] = v;
    }
}

extern "C" void kernel_launch(void* const* d_in, const int* in_sizes, int n_in,
                              void* d_out, int out_size, void* d_ws, size_t ws_size,
                              hipStream_t stream)
{
    const float* props = (const float*)d_in[0];   // (1, N, 4)
    const float* gtl   = (const float*)d_in[1];   // (1, K, C) one-hot
    const float* gtb   = (const float*)d_in[2];   // (1, K, 4)
    float* out = (float*)d_out;

    int n_prop  = in_sizes[0] / 4;
    int K       = in_sizes[2] / 4;
    int C       = in_sizes[1] / K;
    int n_total = n_prop + K;

    int* ws_packed = (int*)d_ws;                       // n_total ints
    int* ws_gtcls  = ws_packed + n_total;              // K ints
    int* ws_fg     = ws_gtcls + ((K + 3) & ~3);        // FG_CAP
    int* ws_bg     = ws_fg + FG_CAP;                   // BG_CAP
    int* ws_nb     = ws_bg + BG_CAP;                   // NB_CAP
    int* ws_cnt    = ws_nb + NB_CAP;                   // 4

    int roi_blocks = (n_total + 255) / 256;
    int gt_blocks  = (K + 255) / 256;

    pt_classify<<<roi_blocks + gt_blocks, 256, 0, stream>>>(
        props, gtb, gtl, ws_packed, ws_gtcls, n_prop, K, C, n_total, roi_blocks);
    pt_compact<<<1, 1024, 0, stream>>>(
        ws_packed, ws_fg, ws_bg, ws_nb, ws_cnt, n_total);
    pt_output<<<BATCH, 128, 0, stream>>>(
        props, gtb, ws_packed, ws_gtcls, ws_fg, ws_bg, ws_nb, ws_cnt,
        out, n_prop, K, C);
}

// Round 2
// 90.305 us; speedup vs baseline: 1.3308x; 1.3308x over previous
//
#include <hip/hip_runtime.h>

#define BATCH   256
#define FG_CAP  64
#define BG_CAP  192
#define NB_CAP  256
#define SPLIT   8          // lanes per ROI in pt_classify
#define ROIS_PB 32         // ROIs per 256-thread block

// ---------------------------------------------------------------------------
// Kernel 1: per-ROI IoU argmax/max vs all GT boxes  +  gt one-hot argmax.
// packed[i] = best_gt_index | (cls << 16), cls: 0=neither, 1=fg, 2=bg
// K-loop split across SPLIT lanes per ROI for wave-level parallelism
// (R1 showed 7% occupancy / 35% VALUBusy with 1 thread/ROI).
// IoU arithmetic uses explicit round-to-nearest intrinsics in the reference's
// exact op order so threshold comparisons match numpy bit-for-bit.
// ---------------------------------------------------------------------------
__global__ __launch_bounds__(256) void pt_classify(
    const float* __restrict__ props, const float* __restrict__ gtb,
    const float* __restrict__ gtl,
    int* __restrict__ packed, int* __restrict__ gtcls,
    int n_prop, int K, int C, int n_total, int roi_blocks)
{
    if ((int)blockIdx.x >= roi_blocks) {
        // gt-class blocks: argmax of one-hot label rows (first-max)
        int t = ((int)blockIdx.x - roi_blocks) * 256 + (int)threadIdx.x;
        if (t < K) {
            const float* row = gtl + (size_t)t * C;
            float best = row[0]; int bc = 0;
            for (int c = 1; c < C; ++c) {
                float v = row[c];
                if (v > best) { best = v; bc = c; }
            }
            gtcls[t] = bc;
        }
        return;
    }

    __shared__ float4 s_gt[512];
    __shared__ float  s_area[512];
    for (int k = threadIdx.x; k < K; k += 256) {
        float x1 = gtb[4*k+0], y1 = gtb[4*k+1], x2 = gtb[4*k+2], y2 = gtb[4*k+3];
        s_gt[k] = make_float4(x1, y1, x2, y2);
        s_area[k] = __fmul_rn(__fadd_rn(__fsub_rn(x2, x1), 1.0f),
                              __fadd_rn(__fsub_rn(y2, y1), 1.0f));
    }
    __syncthreads();

    int roi_local = (int)threadIdx.x / SPLIT;
    int slice     = (int)threadIdx.x & (SPLIT - 1);
    int i = (int)blockIdx.x * ROIS_PB + roi_local;
    if (i >= n_total) return;

    float4 a;
    if (i < n_prop) a = ((const float4*)props)[i];
    else            a = ((const float4*)gtb)[i - n_prop];

    float area_a = __fmul_rn(__fadd_rn(__fsub_rn(a.z, a.x), 1.0f),
                             __fadd_rn(__fsub_rn(a.w, a.y), 1.0f));

    float best = -1.0f; int bestk = 0x7FFFFFFF;
    for (int k = slice; k < K; k += SPLIT) {
        float4 g = s_gt[k];
        float iw = fmaxf(__fadd_rn(__fsub_rn(fminf(a.z, g.z), fmaxf(a.x, g.x)), 1.0f), 0.0f);
        float ih = fmaxf(__fadd_rn(__fsub_rn(fminf(a.w, g.w), fmaxf(a.y, g.y)), 1.0f), 0.0f);
        float inter = __fmul_rn(iw, ih);
        float denom = __fsub_rn(__fadd_rn(area_a, s_area[k]), inter);
        float iou   = __fdiv_rn(inter, denom);
        if (iou > best) { best = iou; bestk = k; }   // strict > == first-max within slice
    }

    // combine the SPLIT slices (consecutive lanes): max iou, ties -> lowest k.
    // Slices partition k, each slice kept its lowest-k max => global first-max.
    #pragma unroll
    for (int m = 1; m < SPLIT; m <<= 1) {
        float ob = __shfl_xor(best, m, 64);
        int   ok = __shfl_xor(bestk, m, 64);
        if (ob > best || (ob == best && ok < bestk)) { best = ob; bestk = ok; }
    }

    if (slice == 0) {
        int cls = 0;
        if (best >= 0.5f)      cls = 1;   // fg
        else if (best >= 0.1f) cls = 2;   // bg
        packed[i] = bestk | (cls << 16);
    }
}

// ---------------------------------------------------------------------------
// Kernel 2: stable (index-ordered) compaction of fg / bg / non-bg lists.
// Single 1024-thread block, 4096 indices per round (int4 loads, 4 ballots
// per class), 2 barriers per round, early exit once 64 fg + 192 bg found.
// ---------------------------------------------------------------------------
__global__ __launch_bounds__(1024) void pt_compact(
    const int* __restrict__ packed,
    int* __restrict__ fg_list, int* __restrict__ bg_list,
    int* __restrict__ nb_list, int* __restrict__ counts, int n_total)
{
    __shared__ int w_fg[16], w_bg[16], w_nb[16];
    __shared__ int run[3];
    __shared__ int done;
    int tid = threadIdx.x;
    if (tid == 0) { run[0] = 0; run[1] = 0; run[2] = 0; done = 0; }
    __syncthreads();

    int lane = tid & 63, wave = tid >> 6;
    unsigned long long ltmask = (1ull << lane) - 1ull;

    for (int base = 0; base < n_total; base += 4096) {
        int idx0 = base + tid * 4;
        int cls[4];
        if (idx0 + 3 < n_total) {
            int4 p = ((const int4*)packed)[(base >> 2) + tid];
            cls[0] = p.x >> 16; cls[1] = p.y >> 16; cls[2] = p.z >> 16; cls[3] = p.w >> 16;
        } else {
            #pragma unroll
            for (int j = 0; j < 4; ++j)
                cls[j] = (idx0 + j < n_total) ? (packed[idx0 + j] >> 16) : -1;
        }

        unsigned long long Bfg[4], Bbg[4], Bnb[4];
        int tf = 0, tb = 0, tn = 0;
        #pragma unroll
        for (int j = 0; j < 4; ++j) {
            Bfg[j] = __ballot(cls[j] == 1);
            Bbg[j] = __ballot(cls[j] == 2);
            Bnb[j] = __ballot(cls[j] == 0 || cls[j] == 1);  // in-range, not bg
            tf += (int)__popcll(Bfg[j]);
            tb += (int)__popcll(Bbg[j]);
            tn += (int)__popcll(Bnb[j]);
        }
        if (lane == 0) { w_fg[wave] = tf; w_bg[wave] = tb; w_nb[wave] = tn; }
        int r0 = run[0], r1 = run[1], r2 = run[2];
        __syncthreads();   // A: wave totals visible; run reads complete

        int pf = 0, pb = 0, pn = 0;
        for (int w = 0; w < wave; ++w) { pf += w_fg[w]; pb += w_bg[w]; pn += w_nb[w]; }
        // item order within the chunk is lane-major: lane l holds indices 4l..4l+3
        int af = 0, ab = 0, an = 0;   // items in earlier j-sublists (all lanes)
        #pragma unroll
        for (int j = 0; j < 4; ++j) {
            // rank = run + earlier-wave + earlier-lane (this j is wrong model) —
            // correct: earlier lanes count ALL their items, so use per-lane
            // cumulative count: lanes<l over all j  +  this lane's j'<j.
            int rfg = r0 + pf + af;
            int rbg = r1 + pb + ab;
            int rnb = r2 + pn + an;
            #pragma unroll
            for (int jj = 0; jj < 4; ++jj) { }  // (no-op; clarity)
            // earlier lanes, all 4 sublists:
            int efg = 0, ebg = 0, enb = 0;
            if (j == 0) {
                #pragma unroll
                for (int jj = 0; jj < 4; ++jj) {
                    efg += (int)__popcll(Bfg[jj] & ltmask);
                    ebg += (int)__popcll(Bbg[jj] & ltmask);
                    enb += (int)__popcll(Bnb[jj] & ltmask);
                }
                af = efg; ab = ebg; an = enb;
                rfg = r0 + pf + af; rbg = r1 + pb + ab; rnb = r2 + pn + an;
            }
            if (cls[j] == 1 && rfg < FG_CAP) fg_list[rfg] = idx0 + j;
            if (cls[j] == 2 && rbg < BG_CAP) bg_list[rbg] = idx0 + j;
            if ((cls[j] == 0 || cls[j] == 1) && rnb < NB_CAP) nb_list[rnb] = idx0 + j;
            // advance this lane's own-item counts
            af += (cls[j] == 1);
            ab += (cls[j] == 2);
            an += (cls[j] == 0 || cls[j] == 1);
        }

        if (tid == 0) {
            int sf = 0, sb = 0, sn = 0;
            for (int w = 0; w < 16; ++w) { sf += w_fg[w]; sb += w_bg[w]; sn += w_nb[w]; }
            run[0] += sf; run[1] += sb; run[2] += sn;
            if (run[0] >= FG_CAP && run[1] >= BG_CAP) done = 1;
        }
        __syncthreads();   // B: run/done update visible
        if (done) break;
    }
    if (tid == 0) { counts[0] = run[0]; counts[1] = run[1]; counts[2] = run[2]; }
}

// ---------------------------------------------------------------------------
// Kernel 3: one block per output slot. Fills rois (4), labels one-hot (C),
// bbox_targets (4C, float4 per class) — every element written (d_out poisoned).
// ---------------------------------------------------------------------------
__global__ __launch_bounds__(128) void pt_output(
    const float* __restrict__ props, const float* __restrict__ gtb,
    const int* __restrict__ packed, const int* __restrict__ gtcls,
    const int* __restrict__ fg_list, const int* __restrict__ bg_list,
    const int* __restrict__ nb_list, const int* __restrict__ counts,
    float* __restrict__ out, int n_prop, int K, int C)
{
    __shared__ float sh[8];     // roi x1 y1 x2 y2, tx ty tw th
    __shared__ int   sh_label;
    int s = blockIdx.x;

    if (threadIdx.x == 0) {
        int fg_total = counts[0], bg_total = counts[1];
        int fg_count = min(FG_CAP, fg_total);
        bool is_fg = (s < fg_count);
        int keep;
        if (is_fg) {
            keep = fg_list[s];
        } else {
            int j = s - fg_count;
            keep = (j < bg_total) ? bg_list[j] : nb_list[j - bg_total];
        }
        int pk = packed[keep];
        int assign = pk & 0xFFFF;
        int label = is_fg ? gtcls[assign] : 0;

        float4 roi;
        if (keep < n_prop) roi = ((const float4*)props)[keep];
        else               roi = ((const float4*)gtb)[keep - n_prop];
        float4 g = ((const float4*)gtb)[assign];

        float ew  = roi.z - roi.x + 1.0f;
        float eh  = roi.w - roi.y + 1.0f;
        float ecx = roi.x + 0.5f * ew;
        float ecy = roi.y + 0.5f * eh;
        float gw  = g.z - g.x + 1.0f;
        float gh  = g.w - g.y + 1.0f;
        float gcx = g.x + 0.5f * gw;
        float gcy = g.y + 0.5f * gh;
        sh[0] = roi.x; sh[1] = roi.y; sh[2] = roi.z; sh[3] = roi.w;
        sh[4] = (gcx - ecx) / ew;
        sh[5] = (gcy - ecy) / eh;
        sh[6] = logf(gw / ew);
        sh[7] = logf(gh / eh);
        sh_label = label;
    }
    __syncthreads();

    int label = sh_label;

    if (threadIdx.x < 4) out[s * 4 + threadIdx.x] = sh[threadIdx.x];

    float* outl = out + 4 * BATCH;
    for (int c = threadIdx.x; c < C; c += 128)
        outl[s * C + c] = (c == label) ? 1.0f : 0.0f;

    // bbox_targets: row = C float4s, float4 j == class j's 4 targets (16B-aligned)
    float4* outb = (float4*)(out + 4 * BATCH + BATCH * C) + (size_t)s * C;
    float4 tv = make_float4(sh[4], sh[5], sh[6], sh[7]);
    float4 zv = make_float4(0.f, 0.f, 0.f, 0.f);
    for (int c = threadIdx.x; c < C; c += 128)
        outb[c] = (label > 0 && c == label) ? tv : zv;
}

extern "C" void kernel_launch(void* const* d_in, const int* in_sizes, int n_in,
                              void* d_out, int out_size, void* d_ws, size_t ws_size,
                              hipStream_t stream)
{
    const float* props = (const float*)d_in[0];   // (1, N, 4)
    const float* gtl   = (const float*)d_in[1];   // (1, K, C) one-hot
    const float* gtb   = (const float*)d_in[2];   // (1, K, 4)
    float* out = (float*)d_out;

    int n_prop  = in_sizes[0] / 4;
    int K       = in_sizes[2] / 4;
    int C       = in_sizes[1] / K;
    int n_total = n_prop + K;

    int* ws_packed = (int*)d_ws;                       // n_total ints (16B aligned)
    int* ws_gtcls  = ws_packed + ((n_total + 3) & ~3); // K ints
    int* ws_fg     = ws_gtcls + ((K + 3) & ~3);        // FG_CAP
    int* ws_bg     = ws_fg + FG_CAP;                   // BG_CAP
    int* ws_nb     = ws_bg + BG_CAP;                   // NB_CAP
    int* ws_cnt    = ws_nb + NB_CAP;                   // 4

    int roi_blocks = (n_total + ROIS_PB - 1) / ROIS_PB;
    int gt_blocks  = (K + 255) / 256;

    pt_classify<<<roi_blocks + gt_blocks, 256, 0, stream>>>(
        props, gtb, gtl, ws_packed, ws_gtcls, n_prop, K, C, n_total, roi_blocks);
    pt_compact<<<1, 1024, 0, stream>>>(
        ws_packed, ws_fg, ws_bg, ws_nb, ws_cnt, n_total);
    pt_output<<<BATCH, 128, 0, stream>>>(
        props, gtb, ws_packed, ws_gtcls, ws_fg, ws_bg, ws_nb, ws_cnt,
        out, n_prop, K, C);
}